// Round 1
// baseline (180.799 us; speedup 1.0000x reference)
//
#include <hip/hip_runtime.h>
#include <cstdint>
#include <cmath>

#define N_WIRESK 8
#define N_RAND   20
#define N_GATES  28
#define TPB      256
#define TOKPB    32
#define E_DIM    512

struct OpsArg { int d[N_GATES]; };

// ---------- host-side replication of np.random.RandomState(0) op list ----------
namespace {
struct MT19937 {
  uint32_t mt[624]; int mti;
  void seed(uint32_t s){
    mt[0]=s;
    for(int i=1;i<624;i++) mt[i]=1812433253u*(mt[i-1]^(mt[i-1]>>30))+(uint32_t)i;
    mti=624;
  }
  uint32_t next(){
    if(mti>=624){
      for(int i=0;i<624;i++){
        uint32_t y=(mt[i]&0x80000000u)|(mt[(i+1)%624]&0x7fffffffu);
        mt[i]=mt[(i+397)%624]^(y>>1)^((y&1u)?0x9908b0dfu:0u);
      }
      mti=0;
    }
    uint32_t y=mt[mti++];
    y^=y>>11; y^=(y<<7)&0x9d2c5680u; y^=(y<<15)&0xefc60000u; y^=y>>18;
    return y;
  }
  uint32_t interval(uint32_t mx){ // uniform on [0, mx], numpy rk_interval
    if(!mx) return 0;
    uint32_t mask=mx; mask|=mask>>1; mask|=mask>>2; mask|=mask>>4; mask|=mask>>8; mask|=mask>>16;
    uint32_t v; do { v=next()&mask; } while(v>mx);
    return v;
  }
};

void build_ops(OpsArg* o){
  MT19937 rs; rs.seed(0);
  for(int i=0;i<N_RAND;i++){
    uint32_t k = rs.interval(3);             // randint(4)
    if(k==3){
      int perm[8]; for(int j=0;j<8;j++) perm[j]=j;
      for(int j=7;j>=1;j--){                 // numpy shuffle (Fisher-Yates down)
        uint32_t t=rs.interval((uint32_t)j);
        int tmp=perm[j]; perm[j]=perm[t]; perm[t]=tmp;
      }
      o->d[i] = 3 | (perm[0]<<2) | (perm[1]<<5);   // cnot c=perm[0] t=perm[1]
    } else {
      uint32_t w = rs.interval(7);           // randint(8)
      o->d[i] = (int)k | ((int)w<<2);        // 0=rx 1=ry 2=rz
    }
  }
  for(int i=0;i<8;i++) o->d[N_RAND+i] = 1 | (i<<2);  // trailing RY(theta[w]) wires 0..7
}
} // namespace

// ---------- fused kernel ----------
// wave = 1 token; amp idx = r*64 + lane (r=0..3). idx bit(7-w) = wire w.
// wires 0,1 -> r-bits (register pairs); wires 2..7 -> lane bits (shfl_xor).

#define PAIR_RYRX(LO,HI)                                        \
  do {                                                          \
    if (kind==1){ /* ry */                                      \
      float nlr = gc*ar[LO] - gs*ar[HI];                        \
      float nli = gc*ai[LO] - gs*ai[HI];                        \
      float nhr = gs*ar[LO] + gc*ar[HI];                        \
      float nhi = gs*ai[LO] + gc*ai[HI];                        \
      ar[LO]=nlr; ai[LO]=nli; ar[HI]=nhr; ai[HI]=nhi;           \
    } else {      /* rx */                                      \
      float nlr = gc*ar[LO] + gs*ai[HI];                        \
      float nli = gc*ai[LO] - gs*ar[HI];                        \
      float nhr = gc*ar[HI] + gs*ai[LO];                        \
      float nhi = gc*ai[HI] - gs*ar[LO];                        \
      ar[LO]=nlr; ai[LO]=nli; ar[HI]=nhr; ai[HI]=nhi;           \
    }                                                           \
  } while(0)

__global__ __launch_bounds__(TPB)
void qffb_kernel(const float* __restrict__ x,
                 const float* __restrict__ ry_theta,
                 const float* __restrict__ rand_params,
                 const float* __restrict__ W1,
                 const float* __restrict__ b1,
                 const float* __restrict__ W2,
                 const float* __restrict__ b2,
                 float* __restrict__ out,
                 OpsArg ops)
{
  __shared__ float cs_c[N_GATES], cs_s[N_GATES];
  __shared__ int   op_d[N_GATES];
  __shared__ float Hs[TOKPB*65];      // h values, padded stride 65
  __shared__ float W2s[16*516];       // W2 chunk transposed: W2s[j][e] = W2[e][lc+j]

  const int tid  = threadIdx.x;
  const int lane = tid & 63;
  const int wave = tid >> 6;

  if (tid < N_GATES){
    op_d[tid] = ops.d[tid];
    float th = (tid < N_RAND) ? rand_params[tid] : ry_theta[tid - N_RAND];
    float sv, cv;
    __sincosf(0.5f*th, &sv, &cv);
    cs_c[tid] = cv; cs_s[tid] = sv;
  }
  __syncthreads();

  // ---------------- phase 1: quantum circuit, 1 token per wave ----------------
  for (int it = 0; it < TOKPB/4; ++it){
    const int tl = wave*(TOKPB/4) + it;
    const int token = blockIdx.x*TOKPB + tl;
    const float* xr = x + (size_t)token*E_DIM;

    float cw[8], sw[8];
    #pragma unroll
    for (int w=0; w<8; ++w){
      float f = xr[w];
      __sincosf(0.5f*f, &sw[w], &cw[w]);
    }
    // product over lane-bit wires 2..7 (idx bits 5..0)
    float lp = 1.0f;
    #pragma unroll
    for (int w=2; w<8; ++w)
      lp *= ((lane >> (7-w)) & 1) ? sw[w] : cw[w];

    float ar[4], ai[4];
    ar[0]=cw[0]*cw[1]*lp; ar[1]=cw[0]*sw[1]*lp;
    ar[2]=sw[0]*cw[1]*lp; ar[3]=sw[0]*sw[1]*lp;
    ai[0]=0.f; ai[1]=0.f; ai[2]=0.f; ai[3]=0.f;

    for (int g=0; g<N_GATES; ++g){
      const int dd = op_d[g];
      const int kind = dd & 3;
      const int wa = (dd>>2) & 7;
      const int wb = (dd>>5) & 7;
      const float gc = cs_c[g], gs = cs_s[g];

      if (kind == 3){ // CNOT control=wa target=wb : new[idx] = old[idx ^ (cbit<<(7-t))]
        float pr[4], pi_[4];
        if (wb >= 2){
          const int m = 1 << (7-wb);
          #pragma unroll
          for (int r=0;r<4;++r){ pr[r]=__shfl_xor(ar[r],m); pi_[r]=__shfl_xor(ai[r],m); }
        } else if (wb == 0){ // partner r^2
          pr[0]=ar[2]; pr[1]=ar[3]; pr[2]=ar[0]; pr[3]=ar[1];
          pi_[0]=ai[2]; pi_[1]=ai[3]; pi_[2]=ai[0]; pi_[3]=ai[1];
        } else {             // partner r^1
          pr[0]=ar[1]; pr[1]=ar[0]; pr[2]=ar[3]; pr[3]=ar[2];
          pi_[0]=ai[1]; pi_[1]=ai[0]; pi_[2]=ai[3]; pi_[3]=ai[2];
        }
        if (wa >= 2){
          const int cb = (lane >> (7-wa)) & 1;
          #pragma unroll
          for (int r=0;r<4;++r){ ar[r] = cb ? pr[r] : ar[r]; ai[r] = cb ? pi_[r] : ai[r]; }
        } else {
          #pragma unroll
          for (int r=0;r<4;++r){
            const int cb = (wa==0) ? ((r>>1)&1) : (r&1);
            if (cb){ ar[r]=pr[r]; ai[r]=pi_[r]; }
          }
        }
      } else if (kind == 2){ // RZ: phase (gc, +/-gs), imag part +gs when bit==1
        if (wa >= 2){
          const int bit = (lane >> (7-wa)) & 1;
          const float pim = bit ? gs : -gs;
          #pragma unroll
          for (int r=0;r<4;++r){
            float nr = gc*ar[r] - pim*ai[r];
            ai[r] = gc*ai[r] + pim*ar[r];
            ar[r] = nr;
          }
        } else {
          #pragma unroll
          for (int r=0;r<4;++r){
            const int bit = (wa==0) ? ((r>>1)&1) : (r&1);
            const float pim = bit ? gs : -gs;
            float nr = gc*ar[r] - pim*ai[r];
            ai[r] = gc*ai[r] + pim*ar[r];
            ar[r] = nr;
          }
        }
      } else {               // RX(kind 0) / RY(kind 1)
        if (wa >= 2){
          const int sh = 7-wa;
          const int m = 1 << sh;
          const int bit = (lane >> sh) & 1;
          const float sg = bit ? gs : -gs;
          #pragma unroll
          for (int r=0;r<4;++r){
            const float prr=__shfl_xor(ar[r],m);
            const float pii=__shfl_xor(ai[r],m);
            if (kind==1){ ar[r]=gc*ar[r]+sg*prr; ai[r]=gc*ai[r]+sg*pii; }
            else        { ar[r]=gc*ar[r]+gs*pii; ai[r]=gc*ai[r]-gs*prr; }
          }
        } else if (wa == 0){
          PAIR_RYRX(0,2); PAIR_RYRX(1,3);
        } else {
          PAIR_RYRX(0,1); PAIR_RYRX(2,3);
        }
      }
    }

    // ---- measurement: expv_w = sum_idx p_idx * (1-2*bit_{7-w}(idx)) ----
    const float p0 = ar[0]*ar[0] + ai[0]*ai[0];
    const float p1 = ar[1]*ar[1] + ai[1]*ai[1];
    const float p2 = ar[2]*ar[2] + ai[2]*ai[2];
    const float p3 = ar[3]*ar[3] + ai[3]*ai[3];
    const float P  = p0+p1+p2+p3;
    float e0 = (p0+p1) - (p2+p3);          // wire0: r bit1
    float e1 = (p0-p1) + (p2-p3);          // wire1: r bit0
    float e2 = ((lane>>5)&1) ? -P : P;
    float e3 = ((lane>>4)&1) ? -P : P;
    float e4 = ((lane>>3)&1) ? -P : P;
    float e5 = ((lane>>2)&1) ? -P : P;
    float e6 = ((lane>>1)&1) ? -P : P;
    float e7 = ( lane     &1) ? -P : P;
    #pragma unroll
    for (int m=1; m<64; m<<=1){
      e0 += __shfl_xor(e0,m); e1 += __shfl_xor(e1,m);
      e2 += __shfl_xor(e2,m); e3 += __shfl_xor(e3,m);
      e4 += __shfl_xor(e4,m); e5 += __shfl_xor(e5,m);
      e6 += __shfl_xor(e6,m); e7 += __shfl_xor(e7,m);
    }

    // ---- h = relu(W1 @ expv + b1), one h per lane ----
    const float4 w1a = *(const float4*)(W1 + lane*8);
    const float4 w1b = *(const float4*)(W1 + lane*8 + 4);
    float h = b1[lane];
    h += w1a.x*e0 + w1a.y*e1 + w1a.z*e2 + w1a.w*e3;
    h += w1b.x*e4 + w1b.y*e5 + w1b.z*e6 + w1b.w*e7;
    Hs[tl*65 + lane] = fmaxf(h, 0.0f);
  }

  // ---------------- phase 3: out = H(32x64) @ W2^T(64x512) + b2 ----------------
  const int eg = tid & 63;   // e tile: [eg*8, eg*8+8)
  const int tg = tid >> 6;   // t tile: [tg*8, tg*8+8)
  float acc[8][8];
  #pragma unroll
  for (int j=0;j<8;++j){
    #pragma unroll
    for (int k=0;k<8;++k) acc[j][k]=0.f;
  }

  for (int lc=0; lc<64; lc+=16){
    __syncthreads();   // also covers phase1->phase3 on first iteration
    // stage W2s[j][e] = W2[e][lc+j], j=0..15, e=0..511
    #pragma unroll
    for (int p=0;p<8;++p){
      const int fidx = (p*256 + tid)*4;     // over 512*16 floats
      const int e  = fidx >> 4;
      const int j0 = fidx & 15;
      const float4 v = *(const float4*)(W2 + e*64 + lc + j0);
      W2s[(j0+0)*516 + e] = v.x;
      W2s[(j0+1)*516 + e] = v.y;
      W2s[(j0+2)*516 + e] = v.z;
      W2s[(j0+3)*516 + e] = v.w;
    }
    __syncthreads();

    #pragma unroll 4
    for (int j=0;j<16;++j){
      const int l = lc + j;
      const float4 wv0 = *(const float4*)(&W2s[j*516 + eg*8]);
      const float4 wv1 = *(const float4*)(&W2s[j*516 + eg*8 + 4]);
      float hv[8];
      #pragma unroll
      for (int jj=0;jj<8;++jj) hv[jj] = Hs[(tg*8+jj)*65 + l];
      #pragma unroll
      for (int jj=0;jj<8;++jj){
        acc[jj][0] += hv[jj]*wv0.x;
        acc[jj][1] += hv[jj]*wv0.y;
        acc[jj][2] += hv[jj]*wv0.z;
        acc[jj][3] += hv[jj]*wv0.w;
        acc[jj][4] += hv[jj]*wv1.x;
        acc[jj][5] += hv[jj]*wv1.y;
        acc[jj][6] += hv[jj]*wv1.z;
        acc[jj][7] += hv[jj]*wv1.w;
      }
    }
  }

  const float4 bv0 = *(const float4*)(b2 + eg*8);
  const float4 bv1 = *(const float4*)(b2 + eg*8 + 4);
  #pragma unroll
  for (int jj=0;jj<8;++jj){
    const int t = tg*8 + jj;
    const int token = blockIdx.x*TOKPB + t;
    float4 o0, o1;
    o0.x = acc[jj][0]+bv0.x; o0.y = acc[jj][1]+bv0.y;
    o0.z = acc[jj][2]+bv0.z; o0.w = acc[jj][3]+bv0.w;
    o1.x = acc[jj][4]+bv1.x; o1.y = acc[jj][5]+bv1.y;
    o1.z = acc[jj][6]+bv1.z; o1.w = acc[jj][7]+bv1.w;
    *(float4*)(out + (size_t)token*E_DIM + eg*8)     = o0;
    *(float4*)(out + (size_t)token*E_DIM + eg*8 + 4) = o1;
  }
}

extern "C" void kernel_launch(void* const* d_in, const int* in_sizes, int n_in,
                              void* d_out, int out_size, void* d_ws, size_t ws_size,
                              hipStream_t stream)
{
  (void)n_in; (void)out_size; (void)d_ws; (void)ws_size;
  OpsArg ops;
  build_ops(&ops);                 // deterministic, same every call (graph-safe)

  const int ntok = in_sizes[0] / E_DIM;     // 16384
  const int grid = ntok / TOKPB;            // 512

  qffb_kernel<<<grid, TPB, 0, stream>>>(
      (const float*)d_in[0],   // x
      (const float*)d_in[1],   // ry_theta
      (const float*)d_in[2],   // rand_params
      (const float*)d_in[3],   // W1
      (const float*)d_in[4],   // b1
      (const float*)d_in[5],   // W2
      (const float*)d_in[6],   // b2
      (float*)d_out, ops);
}

// Round 2
// 145.299 us; speedup vs baseline: 1.2443x; 1.2443x over previous
//
#include <hip/hip_runtime.h>
#include <hip/hip_fp16.h>
#include <cstdint>

#define N_RAND   20
#define N_GATES  28
#define E_DIM    512
#define BT       128   // tokens per B-block
#define BE       128   // e per B-block

struct OpsArg { int d[N_GATES]; };

// ---------- host-side replication of np.random.RandomState(0) op list ----------
namespace {
struct MT19937 {
  uint32_t mt[624]; int mti;
  void seed(uint32_t s){
    mt[0]=s;
    for(int i=1;i<624;i++) mt[i]=1812433253u*(mt[i-1]^(mt[i-1]>>30))+(uint32_t)i;
    mti=624;
  }
  uint32_t next(){
    if(mti>=624){
      for(int i=0;i<624;i++){
        uint32_t y=(mt[i]&0x80000000u)|(mt[(i+1)%624]&0x7fffffffu);
        mt[i]=mt[(i+397)%624]^(y>>1)^((y&1u)?0x9908b0dfu:0u);
      }
      mti=0;
    }
    uint32_t y=mt[mti++];
    y^=y>>11; y^=(y<<7)&0x9d2c5680u; y^=(y<<15)&0xefc60000u; y^=y>>18;
    return y;
  }
  uint32_t interval(uint32_t mx){
    if(!mx) return 0;
    uint32_t mask=mx; mask|=mask>>1; mask|=mask>>2; mask|=mask>>4; mask|=mask>>8; mask|=mask>>16;
    uint32_t v; do { v=next()&mask; } while(v>mx);
    return v;
  }
};

void build_ops(OpsArg* o){
  MT19937 rs; rs.seed(0);
  for(int i=0;i<N_RAND;i++){
    uint32_t k = rs.interval(3);
    if(k==3){
      int perm[8]; for(int j=0;j<8;j++) perm[j]=j;
      for(int j=7;j>=1;j--){
        uint32_t t=rs.interval((uint32_t)j);
        int tmp=perm[j]; perm[j]=perm[t]; perm[t]=tmp;
      }
      o->d[i] = 3 | (perm[0]<<2) | (perm[1]<<5);
    } else {
      uint32_t w = rs.interval(7);
      o->d[i] = (int)k | ((int)w<<2);
    }
  }
  for(int i=0;i<8;i++) o->d[N_RAND+i] = 1 | (i<<2);
}
} // namespace

// ---------- device helpers ----------
__device__ __forceinline__ float bperm(int addr, float v){
  return __int_as_float(__builtin_amdgcn_ds_bpermute(addr, __float_as_int(v)));
}
__device__ __forceinline__ float readlane_f(float v, int l){
  return __int_as_float(__builtin_amdgcn_readlane(__float_as_int(v), l));
}
template<int CTRL>
__device__ __forceinline__ float dpp_mov(float v){
  int s = __float_as_int(v);
  return __int_as_float(__builtin_amdgcn_update_dpp(s, s, CTRL, 0xF, 0xF, false));
}
#define DPP_X1 0xB1   // quad_perm [1,0,3,2]
#define DPP_X2 0x4E   // quad_perm [2,3,0,1]

#define PAIR_RYRX(LO,HI)                                        \
  do {                                                          \
    if (kind==1){ /* ry */                                      \
      float nlr = gc*ar[LO] - gs*ar[HI];                        \
      float nli = gc*ai[LO] - gs*ai[HI];                        \
      float nhr = gs*ar[LO] + gc*ar[HI];                        \
      float nhi = gs*ai[LO] + gc*ai[HI];                        \
      ar[LO]=nlr; ai[LO]=nli; ar[HI]=nhr; ai[HI]=nhi;           \
    } else {      /* rx */                                      \
      float nlr = gc*ar[LO] + gs*ai[HI];                        \
      float nli = gc*ai[LO] - gs*ar[HI];                        \
      float nhr = gc*ar[HI] + gs*ai[LO];                        \
      float nhi = gc*ai[HI] - gs*ar[LO];                        \
      ar[LO]=nlr; ai[LO]=nli; ar[HI]=nhr; ai[HI]=nhi;           \
    }                                                           \
  } while(0)

// ================= Kernel A: circuit + W1, one token per wave =================
__global__ __launch_bounds__(256)
void qcirc_kernel(const float* __restrict__ x,
                  const float* __restrict__ ry_theta,
                  const float* __restrict__ rand_params,
                  const float* __restrict__ W1,
                  const float* __restrict__ b1,
                  __half* __restrict__ Hout,
                  OpsArg ops)
{
  __shared__ float2 cs2[N_GATES];
  const int tid  = threadIdx.x;
  const int lane = tid & 63;
  const int wave = tid >> 6;

  if (tid < N_GATES){
    float th = (tid < N_RAND) ? rand_params[tid] : ry_theta[tid - N_RAND];
    float sv, cv;
    __sincosf(0.5f*th, &sv, &cv);
    cs2[tid] = make_float2(cv, sv);
  }
  __syncthreads();

  const int token = blockIdx.x*4 + wave;
  const float4 xa = *(const float4*)(x + (size_t)token*E_DIM);
  const float4 xb = *(const float4*)(x + (size_t)token*E_DIM + 4);

  float cw[8], sw[8];
  {
    float xs[8] = {xa.x, xa.y, xa.z, xa.w, xb.x, xb.y, xb.z, xb.w};
    #pragma unroll
    for (int w=0; w<8; ++w) __sincosf(0.5f*xs[w], &sw[w], &cw[w]);
  }
  float lp = 1.0f;
  #pragma unroll
  for (int w=2; w<8; ++w)
    lp *= ((lane >> (7-w)) & 1) ? sw[w] : cw[w];

  float ar[4], ai[4];
  ar[0]=cw[0]*cw[1]*lp; ar[1]=cw[0]*sw[1]*lp;
  ar[2]=sw[0]*cw[1]*lp; ar[3]=sw[0]*sw[1]*lp;
  ai[0]=0.f; ai[1]=0.f; ai[2]=0.f; ai[3]=0.f;

  #pragma unroll
  for (int g=0; g<N_GATES; ++g){
    const int dd   = ops.d[g];        // kernarg -> SGPR -> uniform branches
    const int kind = dd & 3;
    const int wa   = (dd>>2) & 7;
    const int wb   = (dd>>5) & 7;
    const float2 cspair = cs2[g];
    const float gc = cspair.x, gs = cspair.y;

    if (kind == 3){ // CNOT c=wa t=wb
      float pr[4], pi_[4];
      if (wb >= 2){
        const int m = 1 << (7-wb);
        const int am = (lane ^ m) << 2;
        #pragma unroll
        for (int r=0;r<4;++r){ pr[r]=bperm(am, ar[r]); pi_[r]=bperm(am, ai[r]); }
      } else if (wb == 0){
        pr[0]=ar[2]; pr[1]=ar[3]; pr[2]=ar[0]; pr[3]=ar[1];
        pi_[0]=ai[2]; pi_[1]=ai[3]; pi_[2]=ai[0]; pi_[3]=ai[1];
      } else {
        pr[0]=ar[1]; pr[1]=ar[0]; pr[2]=ar[3]; pr[3]=ar[2];
        pi_[0]=ai[1]; pi_[1]=ai[0]; pi_[2]=ai[3]; pi_[3]=ai[2];
      }
      if (wa >= 2){
        const int cb = (lane >> (7-wa)) & 1;
        #pragma unroll
        for (int r=0;r<4;++r){ ar[r] = cb ? pr[r] : ar[r]; ai[r] = cb ? pi_[r] : ai[r]; }
      } else {
        #pragma unroll
        for (int r=0;r<4;++r){
          const int cb = (wa==0) ? ((r>>1)&1) : (r&1);
          if (cb){ ar[r]=pr[r]; ai[r]=pi_[r]; }
        }
      }
    } else if (kind == 2){ // RZ
      if (wa >= 2){
        const int bit = (lane >> (7-wa)) & 1;
        const float pim = bit ? gs : -gs;
        #pragma unroll
        for (int r=0;r<4;++r){
          float nr = gc*ar[r] - pim*ai[r];
          ai[r] = gc*ai[r] + pim*ar[r];
          ar[r] = nr;
        }
      } else {
        #pragma unroll
        for (int r=0;r<4;++r){
          const int bit = (wa==0) ? ((r>>1)&1) : (r&1);
          const float pim = bit ? gs : -gs;
          float nr = gc*ar[r] - pim*ai[r];
          ai[r] = gc*ai[r] + pim*ar[r];
          ar[r] = nr;
        }
      }
    } else {               // RX / RY
      if (wa >= 2){
        const int sh = 7-wa;
        const int m  = 1 << sh;
        const int am = (lane ^ m) << 2;
        const int bit = (lane >> sh) & 1;
        const float sg = bit ? gs : -gs;
        #pragma unroll
        for (int r=0;r<4;++r){
          const float prr = bperm(am, ar[r]);
          const float pii = bperm(am, ai[r]);
          if (kind==1){ ar[r]=gc*ar[r]+sg*prr; ai[r]=gc*ai[r]+sg*pii; }
          else        { ar[r]=gc*ar[r]+gs*pii; ai[r]=gc*ai[r]-gs*prr; }
        }
      } else if (wa == 0){
        PAIR_RYRX(0,2); PAIR_RYRX(1,3);
      } else {
        PAIR_RYRX(0,1); PAIR_RYRX(2,3);
      }
    }
  }

  // ---- measurement: e0,e1 plain sums; e2..e7 via one signed WHT of P ----
  const float p0 = ar[0]*ar[0] + ai[0]*ai[0];
  const float p1 = ar[1]*ar[1] + ai[1]*ai[1];
  const float p2 = ar[2]*ar[2] + ai[2]*ai[2];
  const float p3 = ar[3]*ar[3] + ai[3]*ai[3];
  float P  = p0+p1+p2+p3;
  float q0 = (p0+p1) - (p2+p3);
  float q1 = (p0-p1) + (p2-p3);
  float t;
  // m=1 (DPP)
  t = dpp_mov<DPP_X1>(q0); q0 += t;
  t = dpp_mov<DPP_X1>(q1); q1 += t;
  t = dpp_mov<DPP_X1>(P);  P = fmaf((lane&1)? -1.f:1.f, P, t);
  // m=2 (DPP)
  t = dpp_mov<DPP_X2>(q0); q0 += t;
  t = dpp_mov<DPP_X2>(q1); q1 += t;
  t = dpp_mov<DPP_X2>(P);  P = fmaf((lane&2)? -1.f:1.f, P, t);
  // m=4,8,16,32 (bpermute)
  #pragma unroll
  for (int st=2; st<6; ++st){
    const int m = 1<<st;
    const int am = (lane ^ m) << 2;
    q0 += bperm(am, q0);
    q1 += bperm(am, q1);
    t = bperm(am, P);  P = fmaf((lane&m)? -1.f:1.f, P, t);
  }
  const float e2 = readlane_f(P, 32);
  const float e3 = readlane_f(P, 16);
  const float e4 = readlane_f(P, 8);
  const float e5 = readlane_f(P, 4);
  const float e6 = readlane_f(P, 2);
  const float e7 = readlane_f(P, 1);

  // ---- h = relu(W1 @ e + b1), one h per lane; store f16 ----
  const float4 w1a = *(const float4*)(W1 + lane*8);
  const float4 w1b = *(const float4*)(W1 + lane*8 + 4);
  float h = b1[lane];
  h += w1a.x*q0 + w1a.y*q1 + w1a.z*e2 + w1a.w*e3;
  h += w1b.x*e4 + w1b.y*e5 + w1b.z*e6 + w1b.w*e7;
  Hout[(size_t)token*64 + lane] = __float2half(fmaxf(h, 0.0f));
}

// ================= Kernel B: out = H @ W2^T + b2 (f16 dot2) =================
typedef _Float16 v2h __attribute__((ext_vector_type(2)));
union HU { uint32_t u; v2h h; };

__device__ __forceinline__ float fdot2f(uint32_t a, uint32_t b, float c){
  HU ua, ub; ua.u = a; ub.u = b;
#if __has_builtin(__builtin_amdgcn_fdot2)
  return __builtin_amdgcn_fdot2(ua.h, ub.h, c, false);
#else
  return c + (float)ua.h.x*(float)ub.h.x + (float)ua.h.y*(float)ub.h.y;
#endif
}

// LDS row layout: 32 k2-rows, 16 chunks of 8 dwords, chunk g at 8g + 4*(g>>2)
#define ROWSTRIDE 140
__device__ __forceinline__ int chunk_off(int g){ return 8*g + 4*(g>>2); }

__global__ __launch_bounds__(256)
void mlp2_kernel(const __half* __restrict__ Hh,
                 const float* __restrict__ W2,
                 const float* __restrict__ b2,
                 float* __restrict__ out)
{
  __shared__ uint32_t HtL[32*ROWSTRIDE];
  __shared__ uint32_t W2L[32*ROWSTRIDE];
  const int tid = threadIdx.x;
  const int tb  = blockIdx.x & 127;
  const int eb  = blockIdx.x >> 7;
  const int t0  = tb*BT, e0 = eb*BE;

  // stage H (f16): 128 t x 64 k
  #pragma unroll
  for (int i=0;i<4;i++){
    int f = i*256 + tid;            // 0..1023 : 128t x 8 k-octets
    int tt = f >> 3;
    int k8 = (f & 7) * 8;
    uint4 v = *(const uint4*)(Hh + (size_t)(t0+tt)*64 + k8);
    int base = chunk_off(tt>>3) + (tt&7);
    int k2 = k8 >> 1;
    HtL[(k2+0)*ROWSTRIDE + base] = v.x;
    HtL[(k2+1)*ROWSTRIDE + base] = v.y;
    HtL[(k2+2)*ROWSTRIDE + base] = v.z;
    HtL[(k2+3)*ROWSTRIDE + base] = v.w;
  }
  // stage W2 (f32 -> f16): 128 e x 64 k
  #pragma unroll
  for (int i=0;i<8;i++){
    int f = i*256 + tid;            // 0..2047 : 128e x 16 k-quads
    int e  = f >> 4;
    int k4 = (f & 15) * 4;
    float4 v = *(const float4*)(W2 + (size_t)(e0+e)*64 + k4);
    int base = chunk_off(e>>3) + (e&7);
    HU a, b;
    a.h = v2h{(_Float16)v.x, (_Float16)v.y};
    b.h = v2h{(_Float16)v.z, (_Float16)v.w};
    W2L[((k4>>1)+0)*ROWSTRIDE + base] = a.u;
    W2L[((k4>>1)+1)*ROWSTRIDE + base] = b.u;
  }
  __syncthreads();

  const int tg = tid >> 4;          // 0..15 -> tokens [tg*8, tg*8+8)
  const int eg = tid & 15;          // 0..15 -> e [eg*8, eg*8+8)
  const int hoff = chunk_off(tg);
  const int woff = chunk_off(eg);

  float acc[8][8];
  #pragma unroll
  for (int j=0;j<8;++j)
    #pragma unroll
    for (int k=0;k<8;++k) acc[j][k]=0.f;

  #pragma unroll 2
  for (int k2=0; k2<32; ++k2){
    uint4 h0 = *(const uint4*)&HtL[k2*ROWSTRIDE + hoff];
    uint4 h1 = *(const uint4*)&HtL[k2*ROWSTRIDE + hoff + 4];
    uint4 w0 = *(const uint4*)&W2L[k2*ROWSTRIDE + woff];
    uint4 w1 = *(const uint4*)&W2L[k2*ROWSTRIDE + woff + 4];
    uint32_t hh[8] = {h0.x,h0.y,h0.z,h0.w,h1.x,h1.y,h1.z,h1.w};
    uint32_t ww[8] = {w0.x,w0.y,w0.z,w0.w,w1.x,w1.y,w1.z,w1.w};
    #pragma unroll
    for (int j=0;j<8;++j)
      #pragma unroll
      for (int k=0;k<8;++k)
        acc[j][k] = fdot2f(hh[j], ww[k], acc[j][k]);
  }

  const float4 bv0 = *(const float4*)(b2 + e0 + eg*8);
  const float4 bv1 = *(const float4*)(b2 + e0 + eg*8 + 4);
  #pragma unroll
  for (int j=0;j<8;++j){
    const int token = t0 + tg*8 + j;
    float4 o0, o1;
    o0.x = acc[j][0]+bv0.x; o0.y = acc[j][1]+bv0.y;
    o0.z = acc[j][2]+bv0.z; o0.w = acc[j][3]+bv0.w;
    o1.x = acc[j][4]+bv1.x; o1.y = acc[j][5]+bv1.y;
    o1.z = acc[j][6]+bv1.z; o1.w = acc[j][7]+bv1.w;
    *(float4*)(out + (size_t)token*E_DIM + e0 + eg*8)     = o0;
    *(float4*)(out + (size_t)token*E_DIM + e0 + eg*8 + 4) = o1;
  }
}

extern "C" void kernel_launch(void* const* d_in, const int* in_sizes, int n_in,
                              void* d_out, int out_size, void* d_ws, size_t ws_size,
                              hipStream_t stream)
{
  (void)n_in; (void)out_size; (void)ws_size;
  OpsArg ops;
  build_ops(&ops);

  const int ntok = in_sizes[0] / E_DIM;          // 16384
  __half* Hh = (__half*)d_ws;                    // 16384*64*2 = 2 MB scratch

  qcirc_kernel<<<ntok/4, 256, 0, stream>>>(
      (const float*)d_in[0],   // x
      (const float*)d_in[1],   // ry_theta
      (const float*)d_in[2],   // rand_params
      (const float*)d_in[3],   // W1
      (const float*)d_in[4],   // b1
      Hh, ops);

  mlp2_kernel<<<(ntok/BT)*(E_DIM/BE), 256, 0, stream>>>(
      Hh,
      (const float*)d_in[5],   // W2
      (const float*)d_in[6],   // b2
      (float*)d_out);
}

// Round 3
// 121.694 us; speedup vs baseline: 1.4857x; 1.1940x over previous
//
#include <hip/hip_runtime.h>
#include <hip/hip_fp16.h>
#include <cstdint>

#define N_RAND   20
#define N_GATES  28
#define E_DIM    512

struct OpsArg { int d[N_GATES]; };

// ---------- compile-time replication of np.random.RandomState(0) op list ----------
struct MT19937ce {
  uint32_t mt[624] = {};
  int mti = 0;
  constexpr void seed(uint32_t s){
    mt[0]=s;
    for(int i=1;i<624;i++) mt[i]=1812433253u*(mt[i-1]^(mt[i-1]>>30))+(uint32_t)i;
    mti=624;
  }
  constexpr uint32_t next(){
    if(mti>=624){
      for(int i=0;i<624;i++){
        uint32_t y=(mt[i]&0x80000000u)|(mt[(i+1)%624]&0x7fffffffu);
        mt[i]=mt[(i+397)%624]^(y>>1)^((y&1u)?0x9908b0dfu:0u);
      }
      mti=0;
    }
    uint32_t y=mt[mti++];
    y^=y>>11; y^=(y<<7)&0x9d2c5680u; y^=(y<<15)&0xefc60000u; y^=y>>18;
    return y;
  }
  constexpr uint32_t interval(uint32_t mx){
    if(!mx) return 0;
    uint32_t mask=mx; mask|=mask>>1; mask|=mask>>2; mask|=mask>>4; mask|=mask>>8; mask|=mask>>16;
    uint32_t v = next()&mask;
    while(v>mx) v = next()&mask;
    return v;
  }
};

constexpr OpsArg build_ops_ce(){
  MT19937ce rs; rs.seed(0);
  OpsArg o{};
  for(int i=0;i<N_RAND;i++){
    uint32_t k = rs.interval(3);
    if(k==3){
      int perm[8] = {0,1,2,3,4,5,6,7};
      for(int j=7;j>=1;j--){
        uint32_t t=rs.interval((uint32_t)j);
        int tmp=perm[j]; perm[j]=perm[t]; perm[t]=tmp;
      }
      o.d[i] = 3 | (perm[0]<<2) | (perm[1]<<5);
    } else {
      uint32_t w = rs.interval(7);
      o.d[i] = (int)k | ((int)w<<2);
    }
  }
  for(int i=0;i<8;i++) o.d[N_RAND+i] = 1 | (i<<2);
  return o;
}
inline constexpr OpsArg OPS = build_ops_ce();

// ---------- device helpers ----------
__device__ __forceinline__ float readlane_f(float v, int l){
  return __int_as_float(__builtin_amdgcn_readlane(__float_as_int(v), l));
}
template<int CTRL>
__device__ __forceinline__ float dpp_mov(float v){
  int s = __float_as_int(v);
  return __int_as_float(__builtin_amdgcn_update_dpp(s, s, CTRL, 0xF, 0xF, false));
}
// cross-lane xor<M> within 32-lane groups (M in {1,2,4,8,16})
template<int M>
__device__ __forceinline__ float xl(float v){
  if constexpr (M==1)      return dpp_mov<0xB1>(v);            // quad_perm [1,0,3,2]
  else if constexpr (M==2) return dpp_mov<0x4E>(v);            // quad_perm [2,3,0,1]
  else return __int_as_float(__builtin_amdgcn_ds_swizzle(__float_as_int(v), (M<<10)|0x1F));
}
// broadcast lane L (within each 32-lane group)
template<int L>
__device__ __forceinline__ float bcast(float v){
  return __int_as_float(__builtin_amdgcn_ds_swizzle(__float_as_int(v), L<<5));
}

typedef _Float16 v2h __attribute__((ext_vector_type(2)));
typedef _Float16 v8h __attribute__((ext_vector_type(8)));
typedef float    v4f __attribute__((ext_vector_type(4)));
union HU { uint32_t u; v2h h; };

// ---------- fully specialized gate chain ----------
// Per token: amp idx = r*32 + l (l = lane&31). r bits (b2,b1,b0) = wires (0,1,2);
// l bits (b4..b0) = wires (3..7). 2 tokens per wave (lane>=32 -> token+1).
template<int G>
__device__ __forceinline__ void run_gates(float (&ar)[8], float (&ai)[8],
                                          const float (&sgn)[5], int l,
                                          float cv, float sv)
{
  if constexpr (G < N_GATES){
    constexpr int dd   = OPS.d[G];
    constexpr int kind = dd & 3;
    constexpr int wa   = (dd>>2) & 7;
    constexpr int wb   = (dd>>5) & 7;
    const float gc = readlane_f(cv, G);
    const float gs = readlane_f(sv, G);

    if constexpr (kind == 3){                       // ---- CNOT c=wa t=wb ----
      if constexpr (wa < 3 && wb < 3){              // reg-reg: pure register permute
        constexpr int Rc = 4>>wa, Rt = 4>>wb;
        #pragma unroll
        for (int r=0;r<8;r++){
          if ((r & Rc) && !(r & Rt)){
            float t0=ar[r]; ar[r]=ar[r|Rt]; ar[r|Rt]=t0;
            float t1=ai[r]; ai[r]=ai[r|Rt]; ai[r|Rt]=t1;
          }
        }
      } else if constexpr (wa < 3){                 // control reg, target lane
        constexpr int Rc = 4>>wa, Mt = 16>>(wb-3);
        #pragma unroll
        for (int r=0;r<8;r++){
          if (r & Rc){ ar[r]=xl<Mt>(ar[r]); ai[r]=xl<Mt>(ai[r]); }
        }
      } else if constexpr (wb < 3){                 // control lane, target reg
        constexpr int Mc = 16>>(wa-3), Rt = 4>>wb;
        const bool cb = (l & Mc) != 0;
        #pragma unroll
        for (int r=0;r<8;r++){
          if (!(r & Rt)){
            float alo=ar[r], ahi=ar[r|Rt];
            ar[r]    = cb ? ahi : alo;  ar[r|Rt] = cb ? alo : ahi;
            float blo=ai[r], bhi=ai[r|Rt];
            ai[r]    = cb ? bhi : blo;  ai[r|Rt] = cb ? blo : bhi;
          }
        }
      } else {                                      // both lane
        constexpr int Mc = 16>>(wa-3), Mt = 16>>(wb-3);
        const bool cb = (l & Mc) != 0;
        #pragma unroll
        for (int r=0;r<8;r++){
          float pr = xl<Mt>(ar[r]), pi_ = xl<Mt>(ai[r]);
          ar[r] = cb ? pr  : ar[r];
          ai[r] = cb ? pi_ : ai[r];
        }
      }
    } else if constexpr (kind == 2){                // ---- RZ wa ----
      if constexpr (wa < 3){
        constexpr int Rb = 4>>wa;
        #pragma unroll
        for (int r=0;r<8;r++){
          const float pim = (r & Rb) ? gs : -gs;    // folds to +/- at compile time
          float nr = gc*ar[r] - pim*ai[r];
          ai[r] = gc*ai[r] + pim*ar[r];
          ar[r] = nr;
        }
      } else {
        constexpr int SI = wa-3;
        const float pim = sgn[SI]*gs;
        #pragma unroll
        for (int r=0;r<8;r++){
          float nr = gc*ar[r] - pim*ai[r];
          ai[r] = gc*ai[r] + pim*ar[r];
          ar[r] = nr;
        }
      }
    } else if constexpr (kind == 1){                // ---- RY wa ----
      if constexpr (wa < 3){
        constexpr int Rb = 4>>wa;
        #pragma unroll
        for (int r=0;r<8;r++){
          if (!(r & Rb)){
            const int h = r|Rb;
            float lr=ar[r], li=ai[r], hr=ar[h], hii=ai[h];
            ar[r]=gc*lr - gs*hr;  ai[r]=gc*li - gs*hii;
            ar[h]=gs*lr + gc*hr;  ai[h]=gs*li + gc*hii;
          }
        }
      } else {
        constexpr int M = 16>>(wa-3), SI = wa-3;
        const float sg = sgn[SI]*gs;
        #pragma unroll
        for (int r=0;r<8;r++){
          float pr = xl<M>(ar[r]), pi_ = xl<M>(ai[r]);
          ar[r] = gc*ar[r] + sg*pr;
          ai[r] = gc*ai[r] + sg*pi_;
        }
      }
    } else {                                        // ---- RX wa ----
      if constexpr (wa < 3){
        constexpr int Rb = 4>>wa;
        #pragma unroll
        for (int r=0;r<8;r++){
          if (!(r & Rb)){
            const int h = r|Rb;
            float lr=ar[r], li=ai[r], hr=ar[h], hii=ai[h];
            ar[r]=gc*lr + gs*hii;  ai[r]=gc*li - gs*hr;
            ar[h]=gc*hr + gs*li;   ai[h]=gc*hii - gs*lr;
          }
        }
      } else {
        constexpr int M = 16>>(wa-3);
        #pragma unroll
        for (int r=0;r<8;r++){
          float pr = xl<M>(ar[r]), pi_ = xl<M>(ai[r]);
          ar[r] = gc*ar[r] + gs*pi_;
          ai[r] = gc*ai[r] - gs*pr;
        }
      }
    }
    run_gates<G+1>(ar, ai, sgn, l, cv, sv);
  }
}

// ================= Kernel A: circuit + W1, TWO tokens per wave =================
__global__ __launch_bounds__(256)
void qcirc_kernel(const float* __restrict__ x,
                  const float* __restrict__ ry_theta,
                  const float* __restrict__ rand_params,
                  const float* __restrict__ W1,
                  const float* __restrict__ b1,
                  __half* __restrict__ Hout)
{
  const int tid  = threadIdx.x;
  const int lane = tid & 63;
  const int l    = lane & 31;
  const int wave = tid >> 6;
  const int token = blockIdx.x*8 + wave*2 + (lane>>5);

  // per-lane gate angle -> sincos; broadcast later via v_readlane
  float th = 0.f;
  if (lane < N_GATES)
    th = (lane < N_RAND) ? rand_params[lane] : ry_theta[lane - N_RAND];
  float cv, sv;
  __sincosf(0.5f*th, &sv, &cv);

  // token angles
  const float4 xa = *(const float4*)(x + (size_t)token*E_DIM);
  const float4 xb = *(const float4*)(x + (size_t)token*E_DIM + 4);
  float c[8], s[8];
  {
    float xs[8] = {xa.x, xa.y, xa.z, xa.w, xb.x, xb.y, xb.z, xb.w};
    #pragma unroll
    for (int w=0; w<8; ++w) __sincosf(0.5f*xs[w], &s[w], &c[w]);
  }

  float sgn[5];
  sgn[0] = (l&16) ? 1.f : -1.f;
  sgn[1] = (l& 8) ? 1.f : -1.f;
  sgn[2] = (l& 4) ? 1.f : -1.f;
  sgn[3] = (l& 2) ? 1.f : -1.f;
  sgn[4] = (l& 1) ? 1.f : -1.f;

  // initial product state
  float lp = ((l&16)? s[3]:c[3]) * ((l&8)? s[4]:c[4]);
  lp *= ((l&4)? s[5]:c[5]) * ((l&2)? s[6]:c[6]);
  lp *= ((l&1)? s[7]:c[7]);
  const float q00=c[0]*c[1], q01=c[0]*s[1], q10=s[0]*c[1], q11=s[0]*s[1];
  const float c2lp=c[2]*lp, s2lp=s[2]*lp;
  float ar[8], ai[8];
  ar[0]=q00*c2lp; ar[1]=q00*s2lp; ar[2]=q01*c2lp; ar[3]=q01*s2lp;
  ar[4]=q10*c2lp; ar[5]=q10*s2lp; ar[6]=q11*c2lp; ar[7]=q11*s2lp;
  #pragma unroll
  for (int r=0;r<8;r++) ai[r]=0.f;

  run_gates<0>(ar, ai, sgn, l, cv, sv);

  // ---- measurement ----
  float p[8];
  #pragma unroll
  for (int r=0;r<8;r++) p[r] = ar[r]*ar[r] + ai[r]*ai[r];
  const float t1a=p[0]+p[1], t1b=p[2]+p[3], t1c=p[4]+p[5], t1d=p[6]+p[7];
  const float s0a=t1a+t1b, s0b=t1c+t1d;
  float P  = s0a + s0b;
  float e0 = s0a - s0b;                              // wire0 (r bit2)
  float e1 = (t1a+t1c) - (t1b+t1d);                  // wire1 (r bit1)
  float e2 = (p[0]-p[1])+(p[2]-p[3])+(p[4]-p[5])+(p[6]-p[7]); // wire2 (r bit0)

  // butterfly over lane bits: plain sum for e0..e2, signed WHT for P
  {
    float t;
    t=xl<1>(e0); e0+=t;  t=xl<1>(e1); e1+=t;  t=xl<1>(e2); e2+=t;
    t=xl<1>(P);  P = fmaf(-sgn[4], P, t);
    t=xl<2>(e0); e0+=t;  t=xl<2>(e1); e1+=t;  t=xl<2>(e2); e2+=t;
    t=xl<2>(P);  P = fmaf(-sgn[3], P, t);
    t=xl<4>(e0); e0+=t;  t=xl<4>(e1); e1+=t;  t=xl<4>(e2); e2+=t;
    t=xl<4>(P);  P = fmaf(-sgn[2], P, t);
    t=xl<8>(e0); e0+=t;  t=xl<8>(e1); e1+=t;  t=xl<8>(e2); e2+=t;
    t=xl<8>(P);  P = fmaf(-sgn[1], P, t);
    t=xl<16>(e0); e0+=t; t=xl<16>(e1); e1+=t; t=xl<16>(e2); e2+=t;
    t=xl<16>(P); P = fmaf(-sgn[0], P, t);
  }
  const float e3 = bcast<16>(P);
  const float e4 = bcast<8>(P);
  const float e5 = bcast<4>(P);
  const float e6 = bcast<2>(P);
  const float e7 = bcast<1>(P);

  // ---- h = relu(W1 @ e + b1): each lane computes h[2l], h[2l+1] ----
  const float4 wA0 = *(const float4*)(W1 + (size_t)(2*l)*8);
  const float4 wA1 = *(const float4*)(W1 + (size_t)(2*l)*8 + 4);
  const float4 wB0 = *(const float4*)(W1 + (size_t)(2*l+1)*8);
  const float4 wB1 = *(const float4*)(W1 + (size_t)(2*l+1)*8 + 4);
  const float2 bb  = *(const float2*)(b1 + 2*l);
  float h0 = bb.x + wA0.x*e0 + wA0.y*e1 + wA0.z*e2 + wA0.w*e3
                  + wA1.x*e4 + wA1.y*e5 + wA1.z*e6 + wA1.w*e7;
  float h1 = bb.y + wB0.x*e0 + wB0.y*e1 + wB0.z*e2 + wB0.w*e3
                  + wB1.x*e4 + wB1.y*e5 + wB1.z*e6 + wB1.w*e7;
  HU pk;
  pk.h = v2h{(_Float16)fmaxf(h0,0.f), (_Float16)fmaxf(h1,0.f)};
  *(uint32_t*)((char*)Hout + ((size_t)token*64 + 2*l)*2) = pk.u;
}

// ================= W2 fp32 -> f16 converter =================
__global__ __launch_bounds__(256)
void w2cvt_kernel(const float* __restrict__ W2, __half* __restrict__ W2h)
{
  const int i = blockIdx.x*256 + threadIdx.x;     // 8192 threads x 4 floats
  const float4 v = *(const float4*)(W2 + (size_t)i*4);
  HU a, b;
  a.h = v2h{(_Float16)v.x, (_Float16)v.y};
  b.h = v2h{(_Float16)v.z, (_Float16)v.w};
  uint2 o; o.x = a.u; o.y = b.u;
  *(uint2*)((char*)W2h + (size_t)i*8) = o;
}

// ================= Kernel B: out = H @ W2^T + b2 via f16 MFMA =================
// one 16(t) x 16(e) tile per wave, K=64 in two mfma_f32_16x16x32_f16
__global__ __launch_bounds__(256)
void mlp2_mfma(const __half* __restrict__ Hh,
               const __half* __restrict__ W2h,
               const float* __restrict__ b2,
               float* __restrict__ out)
{
  const int tid  = threadIdx.x;
  const int lane = tid & 63;
  const int wid  = blockIdx.x*4 + (tid>>6);
  const int mt   = wid >> 5;            // token tile (0..1023)
  const int nt   = wid & 31;            // e tile (0..31)
  const int rr   = lane & 15;
  const int quad = lane >> 4;

  const v8h a0 = *(const v8h*)(Hh  + ((size_t)(mt*16 + rr))*64 + quad*8);
  const v8h a1 = *(const v8h*)(Hh  + ((size_t)(mt*16 + rr))*64 + 32 + quad*8);
  const v8h b0 = *(const v8h*)(W2h + ((size_t)(nt*16 + rr))*64 + quad*8);
  const v8h b1 = *(const v8h*)(W2h + ((size_t)(nt*16 + rr))*64 + 32 + quad*8);

  v4f acc = {0.f, 0.f, 0.f, 0.f};
  acc = __builtin_amdgcn_mfma_f32_16x16x32_f16(a0, b0, acc, 0, 0, 0);
  acc = __builtin_amdgcn_mfma_f32_16x16x32_f16(a1, b1, acc, 0, 0, 0);

  const float bias = b2[nt*16 + rr];    // C/D: col = lane&15 (e), row = quad*4+reg (t)
  #pragma unroll
  for (int r2=0;r2<4;r2++){
    const int t = mt*16 + quad*4 + r2;
    out[(size_t)t*E_DIM + nt*16 + rr] = acc[r2] + bias;
  }
}

extern "C" void kernel_launch(void* const* d_in, const int* in_sizes, int n_in,
                              void* d_out, int out_size, void* d_ws, size_t ws_size,
                              hipStream_t stream)
{
  (void)n_in; (void)out_size; (void)ws_size;
  const int ntok = in_sizes[0] / E_DIM;            // 16384
  __half* Hh  = (__half*)d_ws;                     // ntok*64*2 = 2 MB
  __half* W2h = (__half*)((char*)d_ws + (size_t)ntok*64*2); // 64 KB

  w2cvt_kernel<<<(E_DIM*64)/(256*4), 256, 0, stream>>>(
      (const float*)d_in[5], W2h);

  qcirc_kernel<<<ntok/8, 256, 0, stream>>>(
      (const float*)d_in[0],   // x
      (const float*)d_in[1],   // ry_theta
      (const float*)d_in[2],   // rand_params
      (const float*)d_in[3],   // W1
      (const float*)d_in[4],   // b1
      Hh);

  mlp2_mfma<<<(ntok/16)*32/4, 256, 0, stream>>>(
      Hh, W2h,
      (const float*)d_in[6],   // b2
      (float*)d_out);
}

// Round 5
// 121.117 us; speedup vs baseline: 1.4928x; 1.0048x over previous
//
#include <hip/hip_runtime.h>
#include <hip/hip_fp16.h>
#include <cstdint>

#define N_RAND   20
#define N_GATES  28
#define E_DIM    512

struct OpsArg { int d[N_GATES]; };

// ---------- compile-time replication of np.random.RandomState(0) op list ----------
struct MT19937ce {
  uint32_t mt[624] = {};
  int mti = 0;
  constexpr void seed(uint32_t s){
    mt[0]=s;
    for(int i=1;i<624;i++) mt[i]=1812433253u*(mt[i-1]^(mt[i-1]>>30))+(uint32_t)i;
    mti=624;
  }
  constexpr uint32_t next(){
    if(mti>=624){
      for(int i=0;i<624;i++){
        uint32_t y=(mt[i]&0x80000000u)|(mt[(i+1)%624]&0x7fffffffu);
        mt[i]=mt[(i+397)%624]^(y>>1)^((y&1u)?0x9908b0dfu:0u);
      }
      mti=0;
    }
    uint32_t y=mt[mti++];
    y^=y>>11; y^=(y<<7)&0x9d2c5680u; y^=(y<<15)&0xefc60000u; y^=y>>18;
    return y;
  }
  constexpr uint32_t interval(uint32_t mx){
    if(!mx) return 0;
    uint32_t mask=mx; mask|=mask>>1; mask|=mask>>2; mask|=mask>>4; mask|=mask>>8; mask|=mask>>16;
    uint32_t v = next()&mask;
    while(v>mx) v = next()&mask;
    return v;
  }
};

constexpr OpsArg build_ops_ce(){
  MT19937ce rs; rs.seed(0);
  OpsArg o{};
  for(int i=0;i<N_RAND;i++){
    uint32_t k = rs.interval(3);
    if(k==3){
      int perm[8] = {0,1,2,3,4,5,6,7};
      for(int j=7;j>=1;j--){
        uint32_t t=rs.interval((uint32_t)j);
        int tmp=perm[j]; perm[j]=perm[t]; perm[t]=tmp;
      }
      o.d[i] = 3 | (perm[0]<<2) | (perm[1]<<5);
    } else {
      uint32_t w = rs.interval(7);
      o.d[i] = (int)k | ((int)w<<2);
    }
  }
  for(int i=0;i<8;i++) o.d[N_RAND+i] = 1 | (i<<2);
  return o;
}
inline constexpr OpsArg OPS = build_ops_ce();

// ---------- device helpers ----------
__device__ __forceinline__ float readlane_f(float v, int l){
  return __int_as_float(__builtin_amdgcn_readlane(__float_as_int(v), l));
}
template<int CTRL>
__device__ __forceinline__ float dpp_mov(float v){
  int s = __float_as_int(v);
  return __int_as_float(__builtin_amdgcn_update_dpp(s, s, CTRL, 0xF, 0xF, false));
}
// cross-lane xor<M> within 32-lane groups (M in {1,2,4,8,16})
template<int M>
__device__ __forceinline__ float xl(float v){
  if constexpr (M==1)      return dpp_mov<0xB1>(v);            // quad_perm [1,0,3,2]
  else if constexpr (M==2) return dpp_mov<0x4E>(v);            // quad_perm [2,3,0,1]
  else return __int_as_float(__builtin_amdgcn_ds_swizzle(__float_as_int(v), (M<<10)|0x1F));
}
// broadcast lane L (within each 32-lane group)
template<int L>
__device__ __forceinline__ float bcast(float v){
  return __int_as_float(__builtin_amdgcn_ds_swizzle(__float_as_int(v), L<<5));
}

typedef _Float16 v2h __attribute__((ext_vector_type(2)));
typedef _Float16 v8h __attribute__((ext_vector_type(8)));
typedef float    v4f __attribute__((ext_vector_type(4)));
union HU  { uint32_t u; v2h h; };

// ---------- fully specialized gate chain ----------
// Per token: amp idx = r*32 + l (l = lane&31). r bits (b2,b1,b0) = wires (0,1,2);
// l bits (b4..b0) = wires (3..7). 2 tokens per wave (lane>=32 -> token+1).
template<int G>
__device__ __forceinline__ void run_gates(float (&ar)[8], float (&ai)[8],
                                          const float (&sgn)[5], int l,
                                          float cv, float sv)
{
  if constexpr (G < N_GATES){
    constexpr int dd   = OPS.d[G];
    constexpr int kind = dd & 3;
    constexpr int wa   = (dd>>2) & 7;
    constexpr int wb   = (dd>>5) & 7;
    const float gc = readlane_f(cv, G);
    const float gs = readlane_f(sv, G);

    if constexpr (kind == 3){                       // ---- CNOT c=wa t=wb ----
      if constexpr (wa < 3 && wb < 3){              // reg-reg: pure register permute
        constexpr int Rc = 4>>wa, Rt = 4>>wb;
        #pragma unroll
        for (int r=0;r<8;r++){
          if ((r & Rc) && !(r & Rt)){
            float t0=ar[r]; ar[r]=ar[r|Rt]; ar[r|Rt]=t0;
            float t1=ai[r]; ai[r]=ai[r|Rt]; ai[r|Rt]=t1;
          }
        }
      } else if constexpr (wa < 3){                 // control reg, target lane
        constexpr int Rc = 4>>wa, Mt = 16>>(wb-3);
        #pragma unroll
        for (int r=0;r<8;r++){
          if (r & Rc){ ar[r]=xl<Mt>(ar[r]); ai[r]=xl<Mt>(ai[r]); }
        }
      } else if constexpr (wb < 3){                 // control lane, target reg
        constexpr int Mc = 16>>(wa-3), Rt = 4>>wb;
        const bool cb = (l & Mc) != 0;
        #pragma unroll
        for (int r=0;r<8;r++){
          if (!(r & Rt)){
            float alo=ar[r], ahi=ar[r|Rt];
            ar[r]    = cb ? ahi : alo;  ar[r|Rt] = cb ? alo : ahi;
            float blo=ai[r], bhi=ai[r|Rt];
            ai[r]    = cb ? bhi : blo;  ai[r|Rt] = cb ? blo : bhi;
          }
        }
      } else {                                      // both lane
        constexpr int Mc = 16>>(wa-3), Mt = 16>>(wb-3);
        const bool cb = (l & Mc) != 0;
        #pragma unroll
        for (int r=0;r<8;r++){
          float pr = xl<Mt>(ar[r]), pi_ = xl<Mt>(ai[r]);
          ar[r] = cb ? pr  : ar[r];
          ai[r] = cb ? pi_ : ai[r];
        }
      }
    } else if constexpr (kind == 2){                // ---- RZ wa ----
      if constexpr (wa < 3){
        constexpr int Rb = 4>>wa;
        #pragma unroll
        for (int r=0;r<8;r++){
          const float pim = (r & Rb) ? gs : -gs;
          float nr = gc*ar[r] - pim*ai[r];
          ai[r] = gc*ai[r] + pim*ar[r];
          ar[r] = nr;
        }
      } else {
        constexpr int SI = wa-3;
        const float pim = sgn[SI]*gs;
        #pragma unroll
        for (int r=0;r<8;r++){
          float nr = gc*ar[r] - pim*ai[r];
          ai[r] = gc*ai[r] + pim*ar[r];
          ar[r] = nr;
        }
      }
    } else if constexpr (kind == 1){                // ---- RY wa ----
      if constexpr (wa < 3){
        constexpr int Rb = 4>>wa;
        #pragma unroll
        for (int r=0;r<8;r++){
          if (!(r & Rb)){
            const int h = r|Rb;
            float lr=ar[r], li=ai[r], hr=ar[h], hii=ai[h];
            ar[r]=gc*lr - gs*hr;  ai[r]=gc*li - gs*hii;
            ar[h]=gs*lr + gc*hr;  ai[h]=gs*li + gc*hii;
          }
        }
      } else {
        constexpr int M = 16>>(wa-3), SI = wa-3;
        const float sg = sgn[SI]*gs;
        #pragma unroll
        for (int r=0;r<8;r++){
          float pr = xl<M>(ar[r]), pi_ = xl<M>(ai[r]);
          ar[r] = gc*ar[r] + sg*pr;
          ai[r] = gc*ai[r] + sg*pi_;
        }
      }
    } else {                                        // ---- RX wa ----
      if constexpr (wa < 3){
        constexpr int Rb = 4>>wa;
        #pragma unroll
        for (int r=0;r<8;r++){
          if (!(r & Rb)){
            const int h = r|Rb;
            float lr=ar[r], li=ai[r], hr=ar[h], hii=ai[h];
            ar[r]=gc*lr + gs*hii;  ai[r]=gc*li - gs*hr;
            ar[h]=gc*hr + gs*li;   ai[h]=gc*hii - gs*lr;
          }
        }
      } else {
        constexpr int M = 16>>(wa-3);
        #pragma unroll
        for (int r=0;r<8;r++){
          float pr = xl<M>(ar[r]), pi_ = xl<M>(ai[r]);
          ar[r] = gc*ar[r] + gs*pi_;
          ai[r] = gc*ai[r] - gs*pr;
        }
      }
    }
    run_gates<G+1>(ar, ai, sgn, l, cv, sv);
  }
}

// ================= Kernel A: circuit + W1, TWO tokens per wave =================
// (byte-identical to the Round-3 passing qcirc_kernel)
__global__ __launch_bounds__(256)
void qcirc_kernel(const float* __restrict__ x,
                  const float* __restrict__ ry_theta,
                  const float* __restrict__ rand_params,
                  const float* __restrict__ W1,
                  const float* __restrict__ b1,
                  __half* __restrict__ Hout)
{
  const int tid  = threadIdx.x;
  const int lane = tid & 63;
  const int l    = lane & 31;
  const int wave = tid >> 6;
  const int token = blockIdx.x*8 + wave*2 + (lane>>5);

  float th = 0.f;
  if (lane < N_GATES)
    th = (lane < N_RAND) ? rand_params[lane] : ry_theta[lane - N_RAND];
  float cv, sv;
  __sincosf(0.5f*th, &sv, &cv);

  const float4 xa = *(const float4*)(x + (size_t)token*E_DIM);
  const float4 xb = *(const float4*)(x + (size_t)token*E_DIM + 4);
  float c[8], s[8];
  {
    float xs[8] = {xa.x, xa.y, xa.z, xa.w, xb.x, xb.y, xb.z, xb.w};
    #pragma unroll
    for (int w=0; w<8; ++w) __sincosf(0.5f*xs[w], &s[w], &c[w]);
  }

  float sgn[5];
  sgn[0] = (l&16) ? 1.f : -1.f;
  sgn[1] = (l& 8) ? 1.f : -1.f;
  sgn[2] = (l& 4) ? 1.f : -1.f;
  sgn[3] = (l& 2) ? 1.f : -1.f;
  sgn[4] = (l& 1) ? 1.f : -1.f;

  float lp = ((l&16)? s[3]:c[3]) * ((l&8)? s[4]:c[4]);
  lp *= ((l&4)? s[5]:c[5]) * ((l&2)? s[6]:c[6]);
  lp *= ((l&1)? s[7]:c[7]);
  const float q00=c[0]*c[1], q01=c[0]*s[1], q10=s[0]*c[1], q11=s[0]*s[1];
  const float c2lp=c[2]*lp, s2lp=s[2]*lp;
  float ar[8], ai[8];
  ar[0]=q00*c2lp; ar[1]=q00*s2lp; ar[2]=q01*c2lp; ar[3]=q01*s2lp;
  ar[4]=q10*c2lp; ar[5]=q10*s2lp; ar[6]=q11*c2lp; ar[7]=q11*s2lp;
  #pragma unroll
  for (int r=0;r<8;r++) ai[r]=0.f;

  run_gates<0>(ar, ai, sgn, l, cv, sv);

  // ---- measurement ----
  float p[8];
  #pragma unroll
  for (int r=0;r<8;r++) p[r] = ar[r]*ar[r] + ai[r]*ai[r];
  const float t1a=p[0]+p[1], t1b=p[2]+p[3], t1c=p[4]+p[5], t1d=p[6]+p[7];
  const float s0a=t1a+t1b, s0b=t1c+t1d;
  float P  = s0a + s0b;
  float e0 = s0a - s0b;
  float e1 = (t1a+t1c) - (t1b+t1d);
  float e2 = (p[0]-p[1])+(p[2]-p[3])+(p[4]-p[5])+(p[6]-p[7]);
  {
    float t;
    t=xl<1>(e0); e0+=t;  t=xl<1>(e1); e1+=t;  t=xl<1>(e2); e2+=t;
    t=xl<1>(P);  P = fmaf(-sgn[4], P, t);
    t=xl<2>(e0); e0+=t;  t=xl<2>(e1); e1+=t;  t=xl<2>(e2); e2+=t;
    t=xl<2>(P);  P = fmaf(-sgn[3], P, t);
    t=xl<4>(e0); e0+=t;  t=xl<4>(e1); e1+=t;  t=xl<4>(e2); e2+=t;
    t=xl<4>(P);  P = fmaf(-sgn[2], P, t);
    t=xl<8>(e0); e0+=t;  t=xl<8>(e1); e1+=t;  t=xl<8>(e2); e2+=t;
    t=xl<8>(P);  P = fmaf(-sgn[1], P, t);
    t=xl<16>(e0); e0+=t; t=xl<16>(e1); e1+=t; t=xl<16>(e2); e2+=t;
    t=xl<16>(P); P = fmaf(-sgn[0], P, t);
  }
  const float e3 = bcast<16>(P);
  const float e4 = bcast<8>(P);
  const float e5 = bcast<4>(P);
  const float e6 = bcast<2>(P);
  const float e7 = bcast<1>(P);

  // ---- h = relu(W1 @ e + b1): each lane computes h[2l], h[2l+1] ----
  const float4 wA0 = *(const float4*)(W1 + (size_t)(2*l)*8);
  const float4 wA1 = *(const float4*)(W1 + (size_t)(2*l)*8 + 4);
  const float4 wB0 = *(const float4*)(W1 + (size_t)(2*l+1)*8);
  const float4 wB1 = *(const float4*)(W1 + (size_t)(2*l+1)*8 + 4);
  const float2 bb  = *(const float2*)(b1 + 2*l);
  float h0 = bb.x + wA0.x*e0 + wA0.y*e1 + wA0.z*e2 + wA0.w*e3
                  + wA1.x*e4 + wA1.y*e5 + wA1.z*e6 + wA1.w*e7;
  float h1 = bb.y + wB0.x*e0 + wB0.y*e1 + wB0.z*e2 + wB0.w*e3
                  + wB1.x*e4 + wB1.y*e5 + wB1.z*e6 + wB1.w*e7;
  HU pk;
  pk.h = v2h{(_Float16)fmaxf(h0,0.f), (_Float16)fmaxf(h1,0.f)};
  *(uint32_t*)((char*)Hout + ((size_t)token*64 + 2*l)*2) = pk.u;
}

// ================= Kernel B: out = H @ W2^T + b2 via f16 MFMA =================
// one 16-token stripe x 64 e per wave (4 tiles), coalesced epilogue via LDS.
#define TS_STRIDE 68
__global__ __launch_bounds__(256)
void mlp2_mfma4(const __half* __restrict__ Hh,
                const float* __restrict__ W2,
                const float* __restrict__ b2,
                float* __restrict__ out)
{
  __shared__ float Ts[4][16*TS_STRIDE];

  const int tid  = threadIdx.x;
  const int lane = tid & 63;
  const int wave = tid >> 6;
  const int wid  = blockIdx.x*4 + wave;
  const int mt   = wid >> 3;            // token tile (0..1023), 16 tokens
  const int ng   = wid & 7;             // e group (0..7), 64 e
  const int rr   = lane & 15;
  const int quad = lane >> 4;

  // A fragment: A[m=rr][k=quad*8+j] (same mapping Round 3 validated)
  const v8h a0 = *(const v8h*)(Hh + ((size_t)(mt*16 + rr))*64 + quad*8);
  const v8h a1 = *(const v8h*)(Hh + ((size_t)(mt*16 + rr))*64 + 32 + quad*8);

  #pragma unroll
  for (int j=0;j<4;++j){
    const int e = ng*64 + j*16 + rr;
    // B fragment from f32 W2, converted in-register (W2 is L2-resident)
    const float4 wa = *(const float4*)(W2 + (size_t)e*64 + quad*8);
    const float4 wb = *(const float4*)(W2 + (size_t)e*64 + quad*8 + 4);
    const float4 wc = *(const float4*)(W2 + (size_t)e*64 + 32 + quad*8);
    const float4 wd = *(const float4*)(W2 + (size_t)e*64 + 32 + quad*8 + 4);
    const v8h b0 = v8h{(_Float16)wa.x,(_Float16)wa.y,(_Float16)wa.z,(_Float16)wa.w,
                      (_Float16)wb.x,(_Float16)wb.y,(_Float16)wb.z,(_Float16)wb.w};
    const v8h b1 = v8h{(_Float16)wc.x,(_Float16)wc.y,(_Float16)wc.z,(_Float16)wc.w,
                      (_Float16)wd.x,(_Float16)wd.y,(_Float16)wd.z,(_Float16)wd.w};
    v4f acc = {0.f,0.f,0.f,0.f};
    acc = __builtin_amdgcn_mfma_f32_16x16x32_f16(a0, b0, acc, 0, 0, 0);
    acc = __builtin_amdgcn_mfma_f32_16x16x32_f16(a1, b1, acc, 0, 0, 0);
    // C/D: row(token) = quad*4+r2, col(e-in-tile) = rr  ->  stage in LDS
    #pragma unroll
    for (int r2=0;r2<4;r2++)
      Ts[wave][(quad*4+r2)*TS_STRIDE + j*16 + rr] = acc[r2];
  }

  __syncthreads();   // order LDS writes before cross-lane reads (per-wave tile, but be safe)

  // epilogue: lane L stores rows 4k+quad, e_local = rr*4..rr*4+3 -> 256B/row segments
  const float4 bias = *(const float4*)(b2 + ng*64 + rr*4);
  #pragma unroll
  for (int k=0;k<4;++k){
    const int row = 4*k + quad;
    float4 v = *(const float4*)&Ts[wave][row*TS_STRIDE + rr*4];
    v.x += bias.x; v.y += bias.y; v.z += bias.z; v.w += bias.w;
    const int t = mt*16 + row;
    *(float4*)(out + (size_t)t*E_DIM + ng*64 + rr*4) = v;
  }
}

extern "C" void kernel_launch(void* const* d_in, const int* in_sizes, int n_in,
                              void* d_out, int out_size, void* d_ws, size_t ws_size,
                              hipStream_t stream)
{
  (void)n_in; (void)out_size; (void)ws_size;
  const int ntok = in_sizes[0] / E_DIM;            // 16384
  __half* Hh = (__half*)d_ws;                      // ntok*64*2 = 2 MB scratch

  qcirc_kernel<<<ntok/8, 256, 0, stream>>>(
      (const float*)d_in[0],   // x
      (const float*)d_in[1],   // ry_theta
      (const float*)d_in[2],   // rand_params
      (const float*)d_in[3],   // W1
      (const float*)d_in[4],   // b1
      Hh);

  mlp2_mfma4<<<(ntok/16)*8/4, 256, 0, stream>>>(
      Hh,
      (const float*)d_in[5],   // W2
      (const float*)d_in[6],   // b2
      (float*)d_out);
}